// Round 1
// baseline (481.679 us; speedup 1.0000x reference)
//
#include <hip/hip_runtime.h>
#include <hip/hip_bf16.h>
#include <stdint.h>

// GraphAttentionLayer: out = softmax(h A h^T, axis=1) @ h,  h = X W^T + b
// N=8192, IN_F=256, D=OUT_F=128. adjacency_matrix (d_in[0]) is UNUSED by the
// reference -> never read (saves 256 MB of HBM traffic).
//
// Precision: scores ~ N(0,128^2), softmax near-one-hot. Output error per row
// ~= w1*w2*delta_score*|h1-h2| -> need delta_score << 0.1. Plain bf16 gives
// ~0.2 (fail); split-bf16 (hi+lo, 3 MFMA products) gives ~1e-3 (safe).
//
// ws layout (bytes):            size
//   h_hi  [8192][128] bf16      2 MB   @ 0
//   h_lo  [8192][128] bf16      2 MB   @ 2 MB
//   q_hi  [8192][128] bf16      2 MB   @ 4 MB   (Q = h @ A)
//   q_lo  [8192][128] bf16      2 MB   @ 6 MB
//   ht    [128][8192] bf16      2 MB   @ 8 MB   (h^T, for V B-operand frags)
//   opart [4][8192][128] f32   16 MB   @ 10 MB  (split-K partials)
//   mpart [4][8192] f32       128 KB   @ 26 MB
//   lpart [4][8192] f32       128 KB   @ 26 MB + 128 KB
// total ~26.3 MB

#define NN 8192
#define INF_ 256
#define D 128
#define BQ 64
#define BK 64
#define KSPLIT 4
#define KSEG (NN / KSPLIT)
#define L2E 1.44269504088896340736f

typedef __attribute__((ext_vector_type(8))) short bf16x8;
typedef __attribute__((ext_vector_type(4))) float f32x4;
typedef __attribute__((ext_vector_type(4))) unsigned int uint4v;

// ---------------------------------------------------------------- prep ----
// h = X@W^T + b (fp32), Q = h@A (fp32); emit bf16 hi/lo splits + h^T(hi).
// 256 blocks x 256 threads; block owns 32 rows. 0.8 GFLOP total.
__global__ __launch_bounds__(256) void prep_kernel(
    const float* __restrict__ X, const float* __restrict__ W,
    const float* __restrict__ bias, const float* __restrict__ A,
    __hip_bfloat16* __restrict__ h_hi, __hip_bfloat16* __restrict__ h_lo,
    __hip_bfloat16* __restrict__ q_hi, __hip_bfloat16* __restrict__ q_lo,
    __hip_bfloat16* __restrict__ ht)
{
    __shared__ float xs[32][INF_];   // 32 KB
    __shared__ float hs[32][D];      // 16 KB
    const int tid  = threadIdx.x;
    const int row0 = blockIdx.x * 32;

    {   // stage X tile (32x256 f32) coalesced
        const f32x4* Xv = (const f32x4*)(X + (size_t)row0 * INF_);
        f32x4* xsv = (f32x4*)&xs[0][0];
        #pragma unroll
        for (int i = 0; i < 8; ++i) xsv[tid + i*256] = Xv[tid + i*256];
    }
    __syncthreads();

    const int c  = tid & 127;   // output column
    const int rh = tid >> 7;    // row half (0/1) -> rows rh*16..rh*16+15

    // ---- h = X W^T + b ----
    float acc[16];
    #pragma unroll
    for (int r = 0; r < 16; ++r) acc[r] = 0.f;
    const f32x4* Wv = (const f32x4*)(W + (size_t)c * INF_);
    for (int k4 = 0; k4 < INF_/4; ++k4) {
        f32x4 w4 = Wv[k4];
        #pragma unroll
        for (int r = 0; r < 16; ++r) {
            f32x4 x4 = ((const f32x4*)&xs[rh*16 + r][0])[k4];  // LDS broadcast
            acc[r] += x4[0]*w4[0] + x4[1]*w4[1] + x4[2]*w4[2] + x4[3]*w4[3];
        }
    }
    const float bc = bias[c];
    #pragma unroll
    for (int r = 0; r < 16; ++r) {
        const int row = rh*16 + r;
        const float hv = acc[r] + bc;
        hs[row][c] = hv;
        const __hip_bfloat16 hi = __float2bfloat16(hv);
        const float lo = hv - __bfloat162float(hi);
        h_hi[(size_t)(row0+row)*D + c] = hi;
        h_lo[(size_t)(row0+row)*D + c] = __float2bfloat16(lo);
        ht  [(size_t)c*NN + row0 + row] = hi;
    }
    __syncthreads();

    // ---- Q = h @ A ----
    float acc2[16];
    #pragma unroll
    for (int r = 0; r < 16; ++r) acc2[r] = 0.f;
    for (int d4 = 0; d4 < D/4; ++d4) {
        f32x4 hv4[16];
        #pragma unroll
        for (int r = 0; r < 16; ++r) hv4[r] = ((const f32x4*)&hs[rh*16 + r][0])[d4];
        #pragma unroll
        for (int dd = 0; dd < 4; ++dd) {
            const float a = A[(size_t)(d4*4 + dd)*D + c];   // coalesced over c
            #pragma unroll
            for (int r = 0; r < 16; ++r) acc2[r] += hv4[r][dd] * a;
        }
    }
    #pragma unroll
    for (int r = 0; r < 16; ++r) {
        const int row = rh*16 + r;
        const float tv = acc2[r];
        const __hip_bfloat16 hi = __float2bfloat16(tv);
        const float lo = tv - __bfloat162float(hi);
        q_hi[(size_t)(row0+row)*D + c] = hi;
        q_lo[(size_t)(row0+row)*D + c] = __float2bfloat16(lo);
    }
}

// --------------------------------------------------------------- flash ----
// grid (128, KSPLIT), 256 threads (4 waves). Wave w owns Q rows q0+16w..+15.
// Per K-tile (BK=64): S strip 16x64 via 16x16x32 bf16 MFMA, 3 split products;
// wave-private online softmax (C-layout rows = quad*4+reg); P -> LDS -> A-frag;
// PV accumulates 16x128 in C-layout regs. Split-K partials to ws.
__global__ __launch_bounds__(256) void flash_kernel(
    const __hip_bfloat16* __restrict__ q_hi, const __hip_bfloat16* __restrict__ q_lo,
    const __hip_bfloat16* __restrict__ k_hi, const __hip_bfloat16* __restrict__ k_lo,
    const __hip_bfloat16* __restrict__ ht,
    float* __restrict__ opart, float* __restrict__ mpart, float* __restrict__ lpart)
{
    // pads: khi/klo row 128+8 (bank rotate 2/row), vt & pbuf row 64+8 (rotate 4/row)
    __shared__ __hip_bfloat16 khi[BK][136];     // 17408 B
    __shared__ __hip_bfloat16 klo[BK][136];     // 17408 B
    __shared__ __hip_bfloat16 vt[D][72];        // 18432 B  (h^T tile: vt[d][j])
    __shared__ __hip_bfloat16 pbuf[4][16][72];  //  9216 B  (per-wave P strips)

    const int tid  = threadIdx.x;
    const int wave = tid >> 6;
    const int lane = tid & 63;
    const int l16  = lane & 15;
    const int quad = lane >> 4;
    const int q0    = blockIdx.x * BQ;
    const int split = blockIdx.y;
    const int jbase = split * KSEG;

    // Q fragments stay in registers for the whole kernel (A-operand layout:
    // m = lane&15, k = 32*t + quad*8 + i)
    bf16x8 aqh[4], aql[4];
    {
        const size_t qrow = (size_t)q0 + wave*16 + l16;
        const __hip_bfloat16* qhp = q_hi + qrow*D;
        const __hip_bfloat16* qlp = q_lo + qrow*D;
        #pragma unroll
        for (int t = 0; t < 4; ++t) {
            aqh[t] = *(const bf16x8*)(qhp + t*32 + quad*8);
            aql[t] = *(const bf16x8*)(qlp + t*32 + quad*8);
        }
    }

    f32x4 oacc[8];
    #pragma unroll
    for (int i = 0; i < 8; ++i) oacc[i] = (f32x4){0.f, 0.f, 0.f, 0.f};
    float mi[4], li[4];
    #pragma unroll
    for (int r = 0; r < 4; ++r) { mi[r] = -1e30f; li[r] = 0.f; }

    for (int it = 0; it < KSEG/BK; ++it) {
        const int j0 = jbase + it * BK;
        __syncthreads();   // previous tile's LDS reads done
        // stage K tile (hi+lo, 64x128) and V^T tile (128x64), 16B chunks
        #pragma unroll
        for (int i = 0; i < 4; ++i) {
            const int chunk = tid + i*256;            // 0..1023
            const int r  = chunk >> 4, c8 = chunk & 15;
            *(uint4v*)(&khi[r][c8*8]) = *(const uint4v*)(k_hi + (size_t)(j0+r)*D + c8*8);
            *(uint4v*)(&klo[r][c8*8]) = *(const uint4v*)(k_lo + (size_t)(j0+r)*D + c8*8);
            const int dd = chunk >> 3, cc = chunk & 7;
            *(uint4v*)(&vt[dd][cc*8]) = *(const uint4v*)(ht + (size_t)dd*NN + j0 + cc*8);
        }
        __syncthreads();

        // S = Q K^T, split-bf16: Qlo*Khi + Qhi*Klo + Qhi*Khi
        f32x4 s[4];
        #pragma unroll
        for (int jt = 0; jt < 4; ++jt) {
            f32x4 acc = (f32x4){0.f, 0.f, 0.f, 0.f};
            #pragma unroll
            for (int t = 0; t < 4; ++t) {
                const bf16x8 bh = *(const bf16x8*)(&khi[jt*16 + l16][t*32 + quad*8]);
                const bf16x8 bl = *(const bf16x8*)(&klo[jt*16 + l16][t*32 + quad*8]);
                acc = __builtin_amdgcn_mfma_f32_16x16x32_bf16(aql[t], bh, acc, 0, 0, 0);
                acc = __builtin_amdgcn_mfma_f32_16x16x32_bf16(aqh[t], bl, acc, 0, 0, 0);
                acc = __builtin_amdgcn_mfma_f32_16x16x32_bf16(aqh[t], bh, acc, 0, 0, 0);
            }
            s[jt] = acc;
        }

        // online softmax; lane's rows are quad*4 + r, cols jt*16 + l16
        float p[4][4];
        #pragma unroll
        for (int r = 0; r < 4; ++r) {
            float v = fmaxf(fmaxf(s[0][r], s[1][r]), fmaxf(s[2][r], s[3][r]));
            #pragma unroll
            for (int m = 1; m < 16; m <<= 1) v = fmaxf(v, __shfl_xor(v, m, 64));
            const float mnew  = fmaxf(mi[r], v);
            const float alpha = exp2f((mi[r] - mnew) * L2E);
            mi[r] = mnew;
            #pragma unroll
            for (int dt = 0; dt < 8; ++dt) oacc[dt][r] *= alpha;
            float sum = 0.f;
            #pragma unroll
            for (int jt = 0; jt < 4; ++jt) {
                const float pv = exp2f((s[jt][r] - mnew) * L2E);
                p[jt][r] = pv;
                sum += pv;
            }
            #pragma unroll
            for (int m = 1; m < 16; m <<= 1) sum += __shfl_xor(sum, m, 64);
            li[r] = li[r] * alpha + sum;
        }

        // P: C-layout -> LDS -> A-operand layout (bf16)
        #pragma unroll
        for (int r = 0; r < 4; ++r)
            #pragma unroll
            for (int jt = 0; jt < 4; ++jt)
                pbuf[wave][quad*4 + r][jt*16 + l16] = __float2bfloat16(p[jt][r]);
        __syncthreads();   // also guarantees P write->read ordering

        bf16x8 ap[2];
        #pragma unroll
        for (int u = 0; u < 2; ++u)
            ap[u] = *(const bf16x8*)(&pbuf[wave][l16][u*32 + quad*8]);
        #pragma unroll
        for (int dt = 0; dt < 8; ++dt)
            #pragma unroll
            for (int u = 0; u < 2; ++u) {
                const bf16x8 bv = *(const bf16x8*)(&vt[dt*16 + l16][u*32 + quad*8]);
                oacc[dt] = __builtin_amdgcn_mfma_f32_16x16x32_bf16(ap[u], bv, oacc[dt], 0, 0, 0);
            }
    }

    // epilogue: split-K partials
    const int qrow_base = q0 + wave*16;
    float* op = opart + ((size_t)split * NN + qrow_base) * D;
    #pragma unroll
    for (int r = 0; r < 4; ++r) {
        const int m = quad*4 + r;
        #pragma unroll
        for (int dt = 0; dt < 8; ++dt)
            op[(size_t)m*D + dt*16 + l16] = oacc[dt][r];
    }
    if (l16 == 0) {
        #pragma unroll
        for (int r = 0; r < 4; ++r) {
            mpart[(size_t)split*NN + qrow_base + quad*4 + r] = mi[r];
            lpart[(size_t)split*NN + qrow_base + quad*4 + r] = li[r];
        }
    }
}

// ------------------------------------------------------------- combine ----
__global__ __launch_bounds__(256) void combine_kernel(
    const float* __restrict__ opart, const float* __restrict__ mpart,
    const float* __restrict__ lpart, float* __restrict__ out)
{
    const int idx = blockIdx.x * 256 + threadIdx.x;   // over 8192*128
    const int q = idx >> 7;
    float m = -1e30f;
    #pragma unroll
    for (int s = 0; s < KSPLIT; ++s) m = fmaxf(m, mpart[(size_t)s*NN + q]);
    float z = 0.f, o = 0.f;
    #pragma unroll
    for (int s = 0; s < KSPLIT; ++s) {
        const float w = exp2f((mpart[(size_t)s*NN + q] - m) * L2E);
        z += lpart[(size_t)s*NN + q] * w;
        o += opart[(size_t)s*NN*D + idx] * w;
    }
    out[idx] = o / z;
}

// ---------------------------------------------------------------- launch --
extern "C" void kernel_launch(void* const* d_in, const int* in_sizes, int n_in,
                              void* d_out, int out_size, void* d_ws, size_t ws_size,
                              hipStream_t stream)
{
    // setup_inputs order: adjacency(0, UNUSED), node_features(1), W(2), b(3), attn_weights(4)
    const float* X = (const float*)d_in[1];
    const float* W = (const float*)d_in[2];
    const float* b = (const float*)d_in[3];
    const float* A = (const float*)d_in[4];
    float* out = (float*)d_out;

    char* ws = (char*)d_ws;
    __hip_bfloat16* h_hi = (__hip_bfloat16*)(ws);
    __hip_bfloat16* h_lo = (__hip_bfloat16*)(ws + (size_t)(2u  << 20));
    __hip_bfloat16* q_hi = (__hip_bfloat16*)(ws + (size_t)(4u  << 20));
    __hip_bfloat16* q_lo = (__hip_bfloat16*)(ws + (size_t)(6u  << 20));
    __hip_bfloat16* ht   = (__hip_bfloat16*)(ws + (size_t)(8u  << 20));
    float* opart = (float*)(ws + (size_t)(10u << 20));
    float* mpart = (float*)(ws + (size_t)(26u << 20));
    float* lpart = (float*)(ws + (size_t)(26u << 20) + (256u << 10));

    prep_kernel<<<NN/32, 256, 0, stream>>>(X, W, b, A, h_hi, h_lo, q_hi, q_lo, ht);
    flash_kernel<<<dim3(NN/BQ, KSPLIT), 256, 0, stream>>>(
        q_hi, q_lo, h_hi, h_lo, ht, opart, mpart, lpart);
    combine_kernel<<<(NN*D)/256, 256, 0, stream>>>(opart, mpart, lpart, out);
}

// Round 2
// 462.021 us; speedup vs baseline: 1.0425x; 1.0425x over previous
//
#include <hip/hip_runtime.h>
#include <hip/hip_bf16.h>
#include <stdint.h>

// GraphAttentionLayer: out = softmax(h A h^T, axis=1) @ h,  h = X W^T + b
// N=8192, IN_F=256, D=OUT_F=128. adjacency_matrix (d_in[0]) is UNUSED.
//
// v2: flash computes S^T = K.Q^T so P exits MFMA directly in A-operand layout
// for PV (k-slot relabeling trick, see comments) -> no P LDS round-trip.
// Each wave owns 32 Q rows (2 i-tiles) -> K/V LDS reads amortized 2x.
//
// ws layout (bytes):            size
//   h_hi  [8192][128] bf16      2 MB   @ 0
//   h_lo  [8192][128] bf16      2 MB   @ 2 MB
//   q_hi  [8192][128] bf16      2 MB   @ 4 MB   (Q = h @ A)
//   q_lo  [8192][128] bf16      2 MB   @ 6 MB
//   ht    [128][8192] bf16      2 MB   @ 8 MB   (h^T, V B-operand staging)
//   opart [8][8192][128] f32   32 MB   @ 10 MB  (split-K partials)
//   mpart [8][8192] f32       256 KB   @ 42 MB
//   lpart [8][8192] f32       256 KB   @ 42 MB + 256 KB

#define NN 8192
#define INF_ 256
#define D 128
#define BQ 128          // Q rows per block (4 waves x 32)
#define BK 64
#define KSPLIT 8
#define KSEG (NN / KSPLIT)
#define L2E 1.44269504088896340736f

typedef __attribute__((ext_vector_type(8))) short bf16x8;
typedef __attribute__((ext_vector_type(4))) short bf16x4;
typedef __attribute__((ext_vector_type(4))) float f32x4;
typedef __attribute__((ext_vector_type(4))) unsigned int uint4v;

// ---------------------------------------------------------------- prep ----
// h = X@W^T + b (fp32), Q = h@A (fp32); emit bf16 hi/lo splits + h^T(hi).
__global__ __launch_bounds__(256) void prep_kernel(
    const float* __restrict__ X, const float* __restrict__ W,
    const float* __restrict__ bias, const float* __restrict__ A,
    __hip_bfloat16* __restrict__ h_hi, __hip_bfloat16* __restrict__ h_lo,
    __hip_bfloat16* __restrict__ q_hi, __hip_bfloat16* __restrict__ q_lo,
    __hip_bfloat16* __restrict__ ht)
{
    __shared__ float xs[32][INF_];   // 32 KB
    __shared__ float hs[32][D];      // 16 KB
    const int tid  = threadIdx.x;
    const int row0 = blockIdx.x * 32;

    {   // stage X tile (32x256 f32) coalesced
        const f32x4* Xv = (const f32x4*)(X + (size_t)row0 * INF_);
        f32x4* xsv = (f32x4*)&xs[0][0];
        #pragma unroll
        for (int i = 0; i < 8; ++i) xsv[tid + i*256] = Xv[tid + i*256];
    }
    __syncthreads();

    const int c  = tid & 127;   // output column
    const int rh = tid >> 7;    // row half (0/1) -> rows rh*16..rh*16+15

    // ---- h = X W^T + b ----
    float acc[16];
    #pragma unroll
    for (int r = 0; r < 16; ++r) acc[r] = 0.f;
    const f32x4* Wv = (const f32x4*)(W + (size_t)c * INF_);
    for (int k4 = 0; k4 < INF_/4; ++k4) {
        f32x4 w4 = Wv[k4];
        #pragma unroll
        for (int r = 0; r < 16; ++r) {
            f32x4 x4 = ((const f32x4*)&xs[rh*16 + r][0])[k4];  // LDS broadcast
            acc[r] += x4[0]*w4[0] + x4[1]*w4[1] + x4[2]*w4[2] + x4[3]*w4[3];
        }
    }
    const float bc = bias[c];
    #pragma unroll
    for (int r = 0; r < 16; ++r) {
        const int row = rh*16 + r;
        const float hv = acc[r] + bc;
        hs[row][c] = hv;
        const __hip_bfloat16 hi = __float2bfloat16(hv);
        const float lo = hv - __bfloat162float(hi);
        h_hi[(size_t)(row0+row)*D + c] = hi;
        h_lo[(size_t)(row0+row)*D + c] = __float2bfloat16(lo);
        ht  [(size_t)c*NN + row0 + row] = hi;
    }
    __syncthreads();

    // ---- Q = h @ A ----
    float acc2[16];
    #pragma unroll
    for (int r = 0; r < 16; ++r) acc2[r] = 0.f;
    for (int d4 = 0; d4 < D/4; ++d4) {
        f32x4 hv4[16];
        #pragma unroll
        for (int r = 0; r < 16; ++r) hv4[r] = ((const f32x4*)&hs[rh*16 + r][0])[d4];
        #pragma unroll
        for (int dd = 0; dd < 4; ++dd) {
            const float a = A[(size_t)(d4*4 + dd)*D + c];   // coalesced over c
            #pragma unroll
            for (int r = 0; r < 16; ++r) acc2[r] += hv4[r][dd] * a;
        }
    }
    #pragma unroll
    for (int r = 0; r < 16; ++r) {
        const int row = rh*16 + r;
        const float tv = acc2[r];
        const __hip_bfloat16 hi = __float2bfloat16(tv);
        const float lo = tv - __bfloat162float(hi);
        q_hi[(size_t)(row0+row)*D + c] = hi;
        q_lo[(size_t)(row0+row)*D + c] = __float2bfloat16(lo);
    }
}

// --------------------------------------------------------------- flash ----
// grid (64, KSPLIT), 256 threads (4 waves). Wave w owns Q rows
// q0 + w*32 + it*16 + l16  (it = 0,1).
//
// MFMA operand facts (verified by round-1 pass):
//   A-frag 16x16x32: lane(l16,quad) holds A[m=l16][k=quad*8+0..7]
//   B-frag:          lane(l16,quad) holds B[n=l16][k=quad*8+0..7]
//   C:               reg r holds      C[m=quad*4+r][n=l16]
//
// S^T = K.Q^T: A=K (m=j), B=Q (n=i). C gives lane: i=l16 (one row!),
// j = jt*16 + quad*4 + r. Softmax reduction = 16 local + shfl_xor(16,32).
// P then sits exactly as PV's A-operand under the k-slot relabeling
//   kslot quad*8+s  <->  j = (s<4 ? jt0 : jt1)*16 + quad*4 + (s&3)
// (valid: MFMA is a sum over kslots; any j<->kslot bijection consistent
// between A and B works). V B-frag = two b64 reads from vt.
__global__ __launch_bounds__(256, 2) void flash_kernel(
    const __hip_bfloat16* __restrict__ q_hi, const __hip_bfloat16* __restrict__ q_lo,
    const __hip_bfloat16* __restrict__ k_hi, const __hip_bfloat16* __restrict__ k_lo,
    const __hip_bfloat16* __restrict__ ht,
    float* __restrict__ opart, float* __restrict__ mpart, float* __restrict__ lpart)
{
    __shared__ __hip_bfloat16 khi[BK][136];   // 17408 B (pad: ~2-way banks)
    __shared__ __hip_bfloat16 klo[BK][136];   // 17408 B
    __shared__ __hip_bfloat16 vt[D][72];      // 18432 B (stride 144B, 8B-aligned)

    const int tid  = threadIdx.x;
    const int wave = tid >> 6;
    const int lane = tid & 63;
    const int l16  = lane & 15;
    const int quad = lane >> 4;
    const int q0    = blockIdx.x * BQ;
    const int split = blockIdx.y;
    const int jbase = split * KSEG;

    // Q fragments (B-operand; n = l16 selects the Q row) for both i-tiles
    bf16x8 bqh[2][4], bql[2][4];
    #pragma unroll
    for (int it = 0; it < 2; ++it) {
        const size_t qrow = (size_t)q0 + wave*32 + it*16 + l16;
        const __hip_bfloat16* qhp = q_hi + qrow*D;
        const __hip_bfloat16* qlp = q_lo + qrow*D;
        #pragma unroll
        for (int t = 0; t < 4; ++t) {
            bqh[it][t] = *(const bf16x8*)(qhp + t*32 + quad*8);
            bql[it][t] = *(const bf16x8*)(qlp + t*32 + quad*8);
        }
    }

    f32x4 oacc[2][8];
    #pragma unroll
    for (int it = 0; it < 2; ++it)
        #pragma unroll
        for (int i = 0; i < 8; ++i) oacc[it][i] = (f32x4){0.f, 0.f, 0.f, 0.f};
    float mi[2] = {-1e30f, -1e30f}, li[2] = {0.f, 0.f};

    for (int tile = 0; tile < KSEG/BK; ++tile) {
        const int j0 = jbase + tile * BK;
        __syncthreads();   // all waves done reading previous tile's LDS
        #pragma unroll
        for (int i = 0; i < 4; ++i) {
            const int chunk = tid + i*256;            // 0..1023
            const int r  = chunk >> 4, c8 = chunk & 15;
            *(uint4v*)(&khi[r][c8*8]) = *(const uint4v*)(k_hi + (size_t)(j0+r)*D + c8*8);
            *(uint4v*)(&klo[r][c8*8]) = *(const uint4v*)(k_lo + (size_t)(j0+r)*D + c8*8);
            const int dd = chunk >> 3, cc = chunk & 7;
            *(uint4v*)(&vt[dd][cc*8]) = *(const uint4v*)(ht + (size_t)dd*NN + j0 + cc*8);
        }
        __syncthreads();

        // ---- S^T strips: st[it][jt] has rows j=jt*16+quad*4+r, col i=l16
        f32x4 st[2][4];
        #pragma unroll
        for (int jt = 0; jt < 4; ++jt) {
            #pragma unroll
            for (int t = 0; t < 4; ++t) {
                const bf16x8 ah = *(const bf16x8*)(&khi[jt*16 + l16][t*32 + quad*8]);
                const bf16x8 al = *(const bf16x8*)(&klo[jt*16 + l16][t*32 + quad*8]);
                #pragma unroll
                for (int it = 0; it < 2; ++it) {
                    f32x4 acc = (t == 0) ? (f32x4){0.f,0.f,0.f,0.f} : st[it][jt];
                    acc = __builtin_amdgcn_mfma_f32_16x16x32_bf16(ah, bql[it][t], acc, 0, 0, 0);
                    acc = __builtin_amdgcn_mfma_f32_16x16x32_bf16(al, bqh[it][t], acc, 0, 0, 0);
                    acc = __builtin_amdgcn_mfma_f32_16x16x32_bf16(ah, bqh[it][t], acc, 0, 0, 0);
                    st[it][jt] = acc;
                }
            }
        }

        // ---- online softmax (each lane owns row i = it*16 + l16)
        bf16x8 pb[2][2];
        #pragma unroll
        for (int it = 0; it < 2; ++it) {
            float vmax = st[it][0][0];
            #pragma unroll
            for (int jt = 0; jt < 4; ++jt)
                #pragma unroll
                for (int r = 0; r < 4; ++r) vmax = fmaxf(vmax, st[it][jt][r]);
            vmax = fmaxf(vmax, __shfl_xor(vmax, 16, 64));
            vmax = fmaxf(vmax, __shfl_xor(vmax, 32, 64));
            const float mnew  = fmaxf(mi[it], vmax);
            const float alpha = exp2f((mi[it] - mnew) * L2E);
            mi[it] = mnew;
            float sum = 0.f;
            #pragma unroll
            for (int jt = 0; jt < 4; ++jt)
                #pragma unroll
                for (int r = 0; r < 4; ++r) {
                    const float pv = exp2f((st[it][jt][r] - mnew) * L2E);
                    st[it][jt][r] = pv;
                    sum += pv;
                }
            sum += __shfl_xor(sum, 16, 64);
            sum += __shfl_xor(sum, 32, 64);
            li[it] = li[it] * alpha + sum;

            // rescale O (C rows are quad*4+r; alpha lives at lane l16==row)
            #pragma unroll
            for (int r = 0; r < 4; ++r) {
                const float ar = __shfl(alpha, quad*4 + r, 64);
                #pragma unroll
                for (int dt = 0; dt < 8; ++dt) oacc[it][dt][r] *= ar;
            }
            // pack P as PV A-operand (kslot relabeling: jt-pair per frag)
            #pragma unroll
            for (int jp = 0; jp < 2; ++jp) {
                bf16x8 f;
                #pragma unroll
                for (int r = 0; r < 4; ++r) {
                    f[r]     = __bfloat16_as_short(__float2bfloat16(st[it][2*jp  ][r]));
                    f[r + 4] = __bfloat16_as_short(__float2bfloat16(st[it][2*jp+1][r]));
                }
                pb[it][jp] = f;
            }
        }

        // ---- PV: O[m=i][n=d], B-frag = V[j(kslot)][d=l16] (two b64 reads)
        #pragma unroll
        for (int dt = 0; dt < 8; ++dt) {
            const __hip_bfloat16* vrow = &vt[dt*16 + l16][0];
            #pragma unroll
            for (int jp = 0; jp < 2; ++jp) {
                const bf16x4 v0 = *(const bf16x4*)(vrow + (2*jp)*16   + quad*4);
                const bf16x4 v1 = *(const bf16x4*)(vrow + (2*jp+1)*16 + quad*4);
                bf16x8 bv;
                #pragma unroll
                for (int r = 0; r < 4; ++r) { bv[r] = v0[r]; bv[r+4] = v1[r]; }
                #pragma unroll
                for (int it = 0; it < 2; ++it)
                    oacc[it][dt] = __builtin_amdgcn_mfma_f32_16x16x32_bf16(
                        pb[it][jp], bv, oacc[it][dt], 0, 0, 0);
            }
        }
    }

    // ---- epilogue: split-K partials
    float* op = opart + ((size_t)split * NN + q0 + wave*32) * D;
    #pragma unroll
    for (int it = 0; it < 2; ++it) {
        #pragma unroll
        for (int r = 0; r < 4; ++r) {
            const int m = it*16 + quad*4 + r;
            #pragma unroll
            for (int dt = 0; dt < 8; ++dt)
                op[(size_t)m*D + dt*16 + l16] = oacc[it][dt][r];
        }
        if (quad == 0) {
            mpart[(size_t)split*NN + q0 + wave*32 + it*16 + l16] = mi[it];
            lpart[(size_t)split*NN + q0 + wave*32 + it*16 + l16] = li[it];
        }
    }
}

// ------------------------------------------------------------- combine ----
__global__ __launch_bounds__(256) void combine_kernel(
    const float* __restrict__ opart, const float* __restrict__ mpart,
    const float* __restrict__ lpart, float* __restrict__ out)
{
    const int idx = blockIdx.x * 256 + threadIdx.x;   // over 8192*128
    const int q = idx >> 7;
    float m = -1e30f;
    #pragma unroll
    for (int s = 0; s < KSPLIT; ++s) m = fmaxf(m, mpart[(size_t)s*NN + q]);
    float z = 0.f, o = 0.f;
    #pragma unroll
    for (int s = 0; s < KSPLIT; ++s) {
        const float w = exp2f((mpart[(size_t)s*NN + q] - m) * L2E);
        z += lpart[(size_t)s*NN + q] * w;
        o += opart[(size_t)s*NN*D + idx] * w;
    }
    out[idx] = o / z;
}

// ---------------------------------------------------------------- launch --
extern "C" void kernel_launch(void* const* d_in, const int* in_sizes, int n_in,
                              void* d_out, int out_size, void* d_ws, size_t ws_size,
                              hipStream_t stream)
{
    // setup_inputs order: adjacency(0, UNUSED), node_features(1), W(2), b(3), attn_weights(4)
    const float* X = (const float*)d_in[1];
    const float* W = (const float*)d_in[2];
    const float* b = (const float*)d_in[3];
    const float* A = (const float*)d_in[4];
    float* out = (float*)d_out;

    char* ws = (char*)d_ws;
    __hip_bfloat16* h_hi = (__hip_bfloat16*)(ws);
    __hip_bfloat16* h_lo = (__hip_bfloat16*)(ws + (size_t)(2u  << 20));
    __hip_bfloat16* q_hi = (__hip_bfloat16*)(ws + (size_t)(4u  << 20));
    __hip_bfloat16* q_lo = (__hip_bfloat16*)(ws + (size_t)(6u  << 20));
    __hip_bfloat16* ht   = (__hip_bfloat16*)(ws + (size_t)(8u  << 20));
    float* opart = (float*)(ws + (size_t)(10u << 20));
    float* mpart = (float*)(ws + (size_t)(42u << 20));
    float* lpart = (float*)(ws + (size_t)(42u << 20) + (256u << 10));

    prep_kernel<<<NN/32, 256, 0, stream>>>(X, W, b, A, h_hi, h_lo, q_hi, q_lo, ht);
    flash_kernel<<<dim3(NN/BQ, KSPLIT), 256, 0, stream>>>(
        q_hi, q_lo, h_hi, h_lo, ht, opart, mpart, lpart);
    combine_kernel<<<(NN*D)/256, 256, 0, stream>>>(opart, mpart, lpart, out);
}